// Round 1
// baseline (776.701 us; speedup 1.0000x reference)
//
#include <hip/hip_runtime.h>

#define NB 32
#define CIN 64
#define TT 300
#define VV 25
#define NI 32
#define CO 128
#define NSLICE (NB*TT)      // 9600
#define NBUCKET 64
#define EPSV 1e-5f
#define SCALEV 0.17677669529663687f   // 1/sqrt(32)
#define NRED (NB*TT*VV)     // 240000

// ---------------------------------------------------------------------------
// K1: one block per (b,t) slice. Computes th, ph, A=softmax, g, out=A@g.
// Writes pre-BN out into d_out (final (b,o,t,v) layout) and accumulates
// per-channel sum/sumsq into atomic buckets in ws.
// ---------------------------------------------------------------------------
__global__ __launch_bounds__(256) void agc_k1(
    const float* __restrict__ x,
    const float* __restrict__ tw, const float* __restrict__ tb,
    const float* __restrict__ pw, const float* __restrict__ pb,
    const float* __restrict__ gw, const float* __restrict__ gb,
    float* __restrict__ out, float* __restrict__ bsum, float* __restrict__ bsq)
{
    const int tid = threadIdx.x;
    // XCD swizzle: XCD k gets contiguous slice range -> adjacent t on same L2
    const int sl = ((blockIdx.x & 7) * (NSLICE/8)) + (blockIdx.x >> 3);
    const int b = sl / TT, t = sl - (sl / TT) * TT;

    __shared__ float xs[CIN][VV];     // 6.4 KB
    __shared__ float th[VV][NI];      // 3.2 KB
    __shared__ float ph[NI][VV];      // 3.2 KB
    __shared__ float As[VV][VV];      // 2.5 KB
    __shared__ float gsh[VV][CO];     // 12.8 KB
    __shared__ float rowm[VV], rows[VV];
    __shared__ float red1[256], red2[256];

    // ---- load x slice: 64 channels x 25 v ----
    const float* xp = x + (size_t)b*CIN*TT*VV + (size_t)t*VV;
    for (int e = tid; e < CIN*VV; e += 256) {
        int c = e / VV, v = e - c*VV;
        xs[c][v] = xp[(size_t)c*TT*VV + v];
    }
    __syncthreads();

    // ---- th[v][i], ph[i][w]: 1600 dot products of length 64 ----
    for (int e = tid; e < 2*VV*NI; e += 256) {
        if (e < VV*NI) {
            int v = e >> 5, i = e & 31;
            const float* wp = tw + i*CIN;
            float acc = tb[i];
            #pragma unroll
            for (int c = 0; c < CIN; ++c) acc = fmaf(xs[c][v], wp[c], acc);
            th[v][i] = acc;
        } else {
            int e2 = e - VV*NI;
            int i = e2 / VV, w = e2 - i*VV;
            const float* wp = pw + i*CIN;
            float acc = pb[i];
            #pragma unroll
            for (int c = 0; c < CIN; ++c) acc = fmaf(xs[c][w], wp[c], acc);
            ph[i][w] = acc;
        }
    }

    // ---- g[v][o]: thread owns channel o, 12-13 v's; weight loaded once/13 FMA
    const int o = tid & (CO-1);
    const int half = tid >> 7;
    const int vbase = half * 13;
    const int nv = 13 - half;       // 13 for half0 (v 0..12), 12 for half1 (v 13..24)
    {
        float acc[13];
        #pragma unroll
        for (int k = 0; k < 13; ++k) acc[k] = 0.f;
        const float* wp = gw + o*CIN;
        for (int c = 0; c < CIN; ++c) {
            float w = wp[c];
            #pragma unroll
            for (int k = 0; k < 13; ++k)
                if (k < nv) acc[k] = fmaf(xs[c][vbase+k], w, acc[k]);
        }
        float bias = gb[o];
        #pragma unroll
        for (int k = 0; k < 13; ++k)
            if (k < nv) gsh[vbase+k][o] = acc[k] + bias;
    }
    __syncthreads();

    // ---- scores: As[v][w] = scale * sum_i th[v][i]*ph[i][w] ----
    for (int e = tid; e < VV*VV; e += 256) {
        int v = e / VV, w = e - (e / VV)*VV;
        float acc = 0.f;
        #pragma unroll
        for (int i = 0; i < NI; ++i) acc = fmaf(th[v][i], ph[i][w], acc);
        As[v][w] = acc * SCALEV;
    }
    __syncthreads();
    if (tid < VV) {
        float m = -3.4e38f;
        #pragma unroll
        for (int w = 0; w < VV; ++w) m = fmaxf(m, As[tid][w]);
        rowm[tid] = m;
    }
    __syncthreads();
    for (int e = tid; e < VV*VV; e += 256) {
        int v = e / VV, w = e - v*VV;
        As[v][w] = __expf(As[v][w] - rowm[v]);
    }
    __syncthreads();
    if (tid < VV) {
        float s = 0.f;
        #pragma unroll
        for (int w = 0; w < VV; ++w) s += As[tid][w];
        rows[tid] = 1.f / s;    // fold normalization into the PV step
    }
    __syncthreads();

    // ---- out[v][o] = (sum_w expA[v][w]*g[w][o]) * rows[v]; write + stats ----
    float s_loc = 0.f, q_loc = 0.f;
    {
        float acc[13];
        #pragma unroll
        for (int k = 0; k < 13; ++k) acc[k] = 0.f;
        for (int w = 0; w < VV; ++w) {
            float gv = gsh[w][o];
            #pragma unroll
            for (int k = 0; k < 13; ++k)
                if (k < nv) acc[k] = fmaf(As[vbase+k][w], gv, acc[k]);
        }
        float* op = out + (size_t)(b*CO + o)*TT*VV + (size_t)t*VV + vbase;
        #pragma unroll
        for (int k = 0; k < 13; ++k)
            if (k < nv) {
                float val = acc[k] * rows[vbase+k];
                op[k] = val;
                s_loc += val;
                q_loc = fmaf(val, val, q_loc);
            }
    }
    red1[tid] = s_loc;
    red2[tid] = q_loc;
    __syncthreads();
    if (tid < CO) {
        float s = red1[tid] + red1[tid + 128];
        float q = red2[tid] + red2[tid + 128];
        int bucket = blockIdx.x & (NBUCKET-1);
        atomicAdd(&bsum[bucket*CO + tid], s);
        atomicAdd(&bsq[bucket*CO + tid], q);
    }
}

// ---------------------------------------------------------------------------
// K2: fold buckets -> per-channel scale/shift  (1 block, 128 threads)
// ---------------------------------------------------------------------------
__global__ void agc_k2(const float* __restrict__ bsum, const float* __restrict__ bsq,
                       const float* __restrict__ gamma, const float* __restrict__ beta,
                       float* __restrict__ scl, float* __restrict__ shf)
{
    const int o = threadIdx.x;
    float s = 0.f, q = 0.f;
    for (int k = 0; k < NBUCKET; ++k) {
        s += bsum[k*CO + o];
        q += bsq[k*CO + o];
    }
    float mean = s / (float)NRED;
    float var  = q / (float)NRED - mean*mean;
    float rstd = rsqrtf(var + EPSV);
    float sc = gamma[o] * rstd;
    scl[o] = sc;
    shf[o] = beta[o] - mean * sc;
}

// ---------------------------------------------------------------------------
// K3: in-place normalize d_out, float4 coalesced
// ---------------------------------------------------------------------------
__global__ __launch_bounds__(256) void agc_k3(
    float* __restrict__ out, const float* __restrict__ scl, const float* __restrict__ shf)
{
    const int n4 = NB*CO*TT*VV/4;      // 7,680,000
    float4* p = (float4*)out;
    for (int i = blockIdx.x*blockDim.x + threadIdx.x; i < n4; i += gridDim.x*blockDim.x) {
        int ch = (i / (TT*VV/4)) & (CO-1);   // (b*128+o) & 127 = o
        float4 v = p[i];
        float sc = scl[ch], sh = shf[ch];
        v.x = fmaf(v.x, sc, sh);
        v.y = fmaf(v.y, sc, sh);
        v.z = fmaf(v.z, sc, sh);
        v.w = fmaf(v.w, sc, sh);
        p[i] = v;
    }
}

extern "C" void kernel_launch(void* const* d_in, const int* in_sizes, int n_in,
                              void* d_out, int out_size, void* d_ws, size_t ws_size,
                              hipStream_t stream) {
    const float* x     = (const float*)d_in[0];
    const float* tw    = (const float*)d_in[1];
    const float* tb    = (const float*)d_in[2];
    const float* pw    = (const float*)d_in[3];
    const float* pb    = (const float*)d_in[4];
    const float* gw    = (const float*)d_in[5];
    const float* gb    = (const float*)d_in[6];
    const float* gamma = (const float*)d_in[7];
    const float* beta  = (const float*)d_in[8];
    float* out = (float*)d_out;
    float* ws  = (float*)d_ws;
    float* bsum = ws;                        // [64][128]
    float* bsq  = ws + NBUCKET*CO;           // [64][128]
    float* scl  = ws + 2*NBUCKET*CO;         // [128]
    float* shf  = ws + 2*NBUCKET*CO + CO;    // [128]

    hipMemsetAsync(d_ws, 0, (size_t)(2*NBUCKET*CO)*sizeof(float), stream);
    agc_k1<<<NSLICE, 256, 0, stream>>>(x, tw, tb, pw, pb, gw, gb, out, bsum, bsq);
    agc_k2<<<1, CO, 0, stream>>>(bsum, bsq, gamma, beta, scl, shf);
    agc_k3<<<2048, 256, 0, stream>>>(out, scl, shf);
}

// Round 2
// 126.126 us; speedup vs baseline: 6.1581x; 6.1581x over previous
//
#include <hip/hip_runtime.h>

#define NB 32
#define CIN 64
#define TT 300
#define VV 25
#define NI 32
#define CO 128
#define NSLICE (NB*TT)      // 9600
#define NBUCKET 64
#define EPSV 1e-5f
#define SCALEV 0.17677669529663687f   // 1/sqrt(32)
#define NRED (NB*TT*VV)     // 240000

using bf16x8 = __attribute__((ext_vector_type(8))) short;
using f32x4  = __attribute__((ext_vector_type(4))) float;

__device__ __forceinline__ unsigned short f2bf(float f) {
    union { float f; unsigned u; } v; v.f = f;
    unsigned u = v.u;
    return (unsigned short)((u + 0x7fffu + ((u >> 16) & 1u)) >> 16);   // RNE
}
__device__ __forceinline__ unsigned pk2(float a, float b) {
    return (unsigned)f2bf(a) | ((unsigned)f2bf(b) << 16);
}

// ---------------------------------------------------------------------------
// K0: pre-swizzle weights into MFMA fragment order (bf16).
// twA/pwA: A-frags  A[i][c]  -> [((it*2+ks)*64 + lane)*8 + j]
// gwB:     B-frags  B[c][o]=gw[o][c] -> [((ot*2+ks)*64 + lane)*8 + j]
// ---------------------------------------------------------------------------
__global__ void agc_k0(const float* __restrict__ tw, const float* __restrict__ pw,
                       const float* __restrict__ gw,
                       unsigned short* __restrict__ twA, unsigned short* __restrict__ pwA,
                       unsigned short* __restrict__ gwB)
{
    int e = blockIdx.x*256 + threadIdx.x;      // 0..12287
    if (e >= 12288) return;
    int j = e & 7, l = (e >> 3) & 63, ks = (e >> 9) & 1, tile = e >> 10;
    int gg = l >> 4, n = l & 15;
    int c = ks*32 + gg*8 + j;
    if (tile < 2)      { int i = tile*16 + n;     twA[e]        = f2bf(tw[i*CIN + c]); }
    else if (tile < 4) { int i = (tile-2)*16 + n; pwA[e - 2048] = f2bf(pw[i*CIN + c]); }
    else               { int o = (tile-4)*16 + n; gwB[e - 4096] = f2bf(gw[o*CIN + c]); }
}

// ---------------------------------------------------------------------------
// K1: one block (4 waves) per (b,t) slice, all matmuls on MFMA.
// LDS strides: xT 72 bf16, th/ph/P 40 bf16, gT 40 bf16 (16B-aligned rows).
// ---------------------------------------------------------------------------
__global__ __launch_bounds__(256, 4) void agc_k1(
    const float* __restrict__ x,
    const float* __restrict__ tb, const float* __restrict__ pb, const float* __restrict__ gb,
    const unsigned short* __restrict__ twA, const unsigned short* __restrict__ pwA,
    const unsigned short* __restrict__ gwB,
    float* __restrict__ out, float* __restrict__ bsum, float* __restrict__ bsq)
{
    __shared__ __align__(16) unsigned char lds[22528];
    unsigned short* xT = (unsigned short*)lds;              // (32, 72)
    unsigned short* th = (unsigned short*)(lds + 4608);     // (32, 40)
    unsigned short* ph = (unsigned short*)(lds + 7168);     // (32, 40)
    unsigned short* Pm = (unsigned short*)(lds + 9728);     // (32, 40)
    unsigned short* gT = (unsigned short*)(lds + 12288);    // (128, 40)
    float* xs = (float*)(lds + 4608);                       // (64, 25) overlay (dead after P0)

    const int tid  = threadIdx.x;
    const int lane = tid & 63;
    const int wid  = tid >> 6;
    const int g    = lane >> 4;       // 0..3
    const int n16  = lane & 15;

    const int sl = ((blockIdx.x & 7) * (NSLICE/8)) + (blockIdx.x >> 3);   // XCD swizzle
    const int b = sl / TT, t = sl - (sl / TT) * TT;

    // ---- P0: stage x slice f32 -> transpose -> xT bf16 (rows 25..31 zero) ----
    const float* xp = x + (size_t)b*CIN*TT*VV + (size_t)t*VV;
    for (int e = tid; e < CIN*VV; e += 256) {
        int c = e / VV, v = e - c*VV;
        xs[e] = xp[(size_t)c*TT*VV + v];
    }
    // zero P pad rows 25..31 (bytes 9728+2000.. — no overlap with xs region)
    if (wid == 2) { for (int e = lane; e < 140; e += 64) ((unsigned*)Pm)[500 + e] = 0u; }
    __syncthreads();
    for (int e = tid; e < 2048; e += 256) {
        int v = e >> 6, c = e & 63;
        float val = (v < VV) ? xs[c*VV + v] : 0.f;
        xT[v*72 + c] = f2bf(val);
    }
    __syncthreads();

    // ---- P1: x fragments (shared by th/ph/g), then per-wave matmuls ----
    bf16x8 xf[2][2];
    #pragma unroll
    for (int rt = 0; rt < 2; ++rt)
        #pragma unroll
        for (int ks = 0; ks < 2; ++ks)
            xf[rt][ks] = *(const bf16x8*)&xT[(rt*16 + n16)*72 + ks*32 + g*8];

    auto do_g = [&](int ot) {
        float gbias = gb[ot*16 + n16];
        #pragma unroll
        for (int wt = 0; wt < 2; ++wt) {
            f32x4 acc = {gbias, gbias, gbias, gbias};
            #pragma unroll
            for (int ks = 0; ks < 2; ++ks) {
                bf16x8 bf = *(const bf16x8*)&gwB[((ot*2 + ks)*64 + lane)*8];
                acc = __builtin_amdgcn_mfma_f32_16x16x32_bf16(xf[wt][ks], bf, acc, 0, 0, 0);
            }
            // D(w,o): rows w=wt*16+g*4+r, col o=ot*16+n16 -> gT[o][w0..w0+3] packed
            *(uint2*)&gT[(ot*16 + n16)*40 + wt*16 + g*4] =
                make_uint2(pk2(acc[0], acc[1]), pk2(acc[2], acc[3]));
        }
    };
    auto do_proj = [&](const unsigned short* wA, const float* bias, unsigned short* dst) {
        #pragma unroll
        for (int it = 0; it < 2; ++it) {
            int i0 = it*16 + g*4;
            f32x4 binit = {bias[i0], bias[i0+1], bias[i0+2], bias[i0+3]};
            bf16x8 a0 = *(const bf16x8*)&wA[((it*2 + 0)*64 + lane)*8];
            bf16x8 a1 = *(const bf16x8*)&wA[((it*2 + 1)*64 + lane)*8];
            #pragma unroll
            for (int vt = 0; vt < 2; ++vt) {
                f32x4 acc = binit;
                acc = __builtin_amdgcn_mfma_f32_16x16x32_bf16(a0, xf[vt][0], acc, 0, 0, 0);
                acc = __builtin_amdgcn_mfma_f32_16x16x32_bf16(a1, xf[vt][1], acc, 0, 0, 0);
                // D(i,v): rows i=i0..i0+3, col v=vt*16+n16 -> dst[v][i0..] packed
                *(uint2*)&dst[(vt*16 + n16)*40 + i0] =
                    make_uint2(pk2(acc[0], acc[1]), pk2(acc[2], acc[3]));
            }
        }
    };

    if (wid == 0)      { do_proj(twA, tb, th); do_g(6); }
    else if (wid == 1) { do_proj(pwA, pb, ph); do_g(7); }
    else               { int base = (wid - 2)*3; do_g(base); do_g(base+1); do_g(base+2); }
    __syncthreads();

    // ---- P2: scores + softmax (waves 0,1; vt = wid) ----
    if (wid < 2) {
        const int vt = wid;
        bf16x8 af = *(const bf16x8*)&th[(vt*16 + n16)*40 + g*8];
        bf16x8 b0 = *(const bf16x8*)&ph[(n16)*40 + g*8];
        bf16x8 b1 = *(const bf16x8*)&ph[(16 + n16)*40 + g*8];
        f32x4 z = {0.f, 0.f, 0.f, 0.f};
        f32x4 d0 = __builtin_amdgcn_mfma_f32_16x16x32_bf16(af, b0, z, 0, 0, 0);
        f32x4 d1 = __builtin_amdgcn_mfma_f32_16x16x32_bf16(af, b1, z, 0, 0, 0);
        const int c = n16;
        const bool cval = (c <= 8);    // col 16+c < 25
        #pragma unroll
        for (int r = 0; r < 4; ++r) {
            float v0 = d0[r]*SCALEV;
            float v1 = cval ? d1[r]*SCALEV : -3.4e38f;
            float m = fmaxf(v0, v1);
            m = fmaxf(m, __shfl_xor(m, 1)); m = fmaxf(m, __shfl_xor(m, 2));
            m = fmaxf(m, __shfl_xor(m, 4)); m = fmaxf(m, __shfl_xor(m, 8));
            float e0 = __expf(v0 - m);
            float e1 = cval ? __expf(v1 - m) : 0.f;
            float s = e0 + e1;
            s += __shfl_xor(s, 1); s += __shfl_xor(s, 2);
            s += __shfl_xor(s, 4); s += __shfl_xor(s, 8);
            float rinv = 1.f / s;
            int v = vt*16 + g*4 + r;
            if (v < VV) {
                Pm[v*40 + c]      = f2bf(e0 * rinv);
                Pm[v*40 + 16 + c] = f2bf(e1 * rinv);   // zeros for c>8 pad cols 25..31
            }
        }
    }
    __syncthreads();

    // ---- P3: out = P @ g, direct global store + BN stats ----
    bf16x8 pa0 = *(const bf16x8*)&Pm[(n16)*40 + g*8];
    bf16x8 pa1 = *(const bf16x8*)&Pm[(16 + n16)*40 + g*8];
    const int bkt = blockIdx.x & (NBUCKET-1);
    #pragma unroll
    for (int k = 0; k < 2; ++k) {
        int ot = wid*2 + k;
        int o  = ot*16 + n16;
        bf16x8 bf = *(const bf16x8*)&gT[o*40 + g*8];
        f32x4 z = {0.f, 0.f, 0.f, 0.f};
        f32x4 e0 = __builtin_amdgcn_mfma_f32_16x16x32_bf16(pa0, bf, z, 0, 0, 0);
        f32x4 e1 = __builtin_amdgcn_mfma_f32_16x16x32_bf16(pa1, bf, z, 0, 0, 0);
        float* op = out + (size_t)(b*CO + o)*TT*VV + (size_t)t*VV;
        int v0 = g*4;
        float s = 0.f, q = 0.f;
        #pragma unroll
        for (int r = 0; r < 4; ++r) {
            op[v0 + r] = e0[r]; s += e0[r]; q = fmaf(e0[r], e0[r], q);
        }
        #pragma unroll
        for (int r = 0; r < 4; ++r) {
            int v = 16 + v0 + r;
            if (v < VV) { op[v] = e1[r]; s += e1[r]; q = fmaf(e1[r], e1[r], q); }
        }
        s += __shfl_xor(s, 16); s += __shfl_xor(s, 32);
        q += __shfl_xor(q, 16); q += __shfl_xor(q, 32);
        if (lane < 16) {
            atomicAdd(&bsum[bkt*CO + o], s);
            atomicAdd(&bsq[bkt*CO + o], q);
        }
    }
}

// ---------------------------------------------------------------------------
// K2: fold buckets -> per-channel scale/shift  (1 block, 128 threads)
// ---------------------------------------------------------------------------
__global__ void agc_k2(const float* __restrict__ bsum, const float* __restrict__ bsq,
                       const float* __restrict__ gamma, const float* __restrict__ beta,
                       float* __restrict__ scl, float* __restrict__ shf)
{
    const int o = threadIdx.x;
    float s = 0.f, q = 0.f;
    for (int k = 0; k < NBUCKET; ++k) { s += bsum[k*CO + o]; q += bsq[k*CO + o]; }
    float mean = s / (float)NRED;
    float var  = q / (float)NRED - mean*mean;
    float rstd = rsqrtf(var + EPSV);
    float sc = gamma[o] * rstd;
    scl[o] = sc;
    shf[o] = beta[o] - mean * sc;
}

// ---------------------------------------------------------------------------
// K3: in-place normalize d_out, float4 coalesced
// ---------------------------------------------------------------------------
__global__ __launch_bounds__(256) void agc_k3(
    float* __restrict__ out, const float* __restrict__ scl, const float* __restrict__ shf)
{
    const int n4 = NB*CO*TT*VV/4;
    float4* p = (float4*)out;
    for (int i = blockIdx.x*blockDim.x + threadIdx.x; i < n4; i += gridDim.x*blockDim.x) {
        int ch = (i / (TT*VV/4)) & (CO-1);
        float4 v = p[i];
        float sc = scl[ch], sh = shf[ch];
        v.x = fmaf(v.x, sc, sh);
        v.y = fmaf(v.y, sc, sh);
        v.z = fmaf(v.z, sc, sh);
        v.w = fmaf(v.w, sc, sh);
        p[i] = v;
    }
}

extern "C" void kernel_launch(void* const* d_in, const int* in_sizes, int n_in,
                              void* d_out, int out_size, void* d_ws, size_t ws_size,
                              hipStream_t stream) {
    const float* x     = (const float*)d_in[0];
    const float* tw    = (const float*)d_in[1];
    const float* tb    = (const float*)d_in[2];
    const float* pw    = (const float*)d_in[3];
    const float* pb    = (const float*)d_in[4];
    const float* gw    = (const float*)d_in[5];
    const float* gb    = (const float*)d_in[6];
    const float* gamma = (const float*)d_in[7];
    const float* beta  = (const float*)d_in[8];
    float* out = (float*)d_out;
    float* ws  = (float*)d_ws;
    float* bsum = ws;                         // [64][128]
    float* bsq  = ws + NBUCKET*CO;            // [64][128]
    float* scl  = ws + 2*NBUCKET*CO;          // [128]
    float* shf  = ws + 2*NBUCKET*CO + CO;     // [128]
    unsigned short* twA = (unsigned short*)(ws + 2*NBUCKET*CO + 2*CO);  // 2048 bf16
    unsigned short* pwA = twA + 2048;                                    // 2048 bf16
    unsigned short* gwB = twA + 4096;                                    // 8192 bf16

    hipMemsetAsync(d_ws, 0, (size_t)(2*NBUCKET*CO)*sizeof(float), stream);
    agc_k0<<<48, 256, 0, stream>>>(tw, pw, gw, twA, pwA, gwB);
    agc_k1<<<NSLICE, 256, 0, stream>>>(x, tb, pb, gb, twA, pwA, gwB, out, bsum, bsq);
    agc_k2<<<1, CO, 0, stream>>>(bsum, bsq, gamma, beta, scl, shf);
    agc_k3<<<2048, 256, 0, stream>>>(out, scl, shf);
}